// Round 2
// baseline (206.041 us; speedup 1.0000x reference)
//
#include <hip/hip_runtime.h>

// YOLOv1 loss, MI355X. NB=2, NC=20, GS=7, BATCH=16384.
// preds/targets: (16384,7,7,30) f32 -> out: 3 f32 [loss_boxes, loss_object, loss_class].
//
// R2: fully-coalesced float4 global->LDS staging (global_load_lds w=16, linear LDS),
// per-cell compute from LDS, single fused kernel with last-block-done reduction.

#define NBX 2
#define NCLS 20
constexpr int   CH      = 5 * NBX + NCLS;      // 30 dwords per cell
constexpr int   NCELL   = 16384 * 7 * 7;       // 802816
constexpr float INV_GS  = 1.0f / 7.0f;
constexpr float INV_BS  = 1.0f / 16384.0f;
constexpr float L_COORD = 5.0f;
constexpr float L_NOOBJ = 0.5f;
constexpr int   BLK     = 256;
constexpr int   NBLK    = NCELL / BLK;         // 3136 exactly
constexpr int   DWB     = BLK * CH;            // 7680 dwords staged per array per block
constexpr int   F4B     = DWB / 4;             // 1920 float4 per array per block

__device__ __forceinline__ void load_lds16(const float4* gsrc, const float* ldst) {
    __builtin_amdgcn_global_load_lds(
        (const __attribute__((address_space(1))) unsigned int*)gsrc,
        (__attribute__((address_space(3))) unsigned int*)ldst,
        16, 0, 0);
}

__global__ __launch_bounds__(BLK) void yolo_loss_fused(
    const float* __restrict__ preds,
    const float* __restrict__ targets,
    unsigned int* __restrict__ counter,   // zeroed per call
    float* __restrict__ part,             // [NBLK][3]
    float* __restrict__ out)              // [3]
{
    __shared__ float sP[DWB];
    __shared__ float sT[DWB];

    const int tid  = threadIdx.x;
    const int wid  = tid >> 6;
    const int lane = tid & 63;
    const int bid  = blockIdx.x;

    // ---- stage: coalesced float4 global -> linear LDS (wave-uniform dest base) ----
    {
        const float4* gp4 = reinterpret_cast<const float4*>(preds   + (size_t)bid * DWB);
        const float4* gt4 = reinterpret_cast<const float4*>(targets + (size_t)bid * DWB);
        #pragma unroll
        for (int i = 0; i < 8; ++i) {
            const int base = i * 256 + wid * 64;   // float4 units, wave-uniform
            if (base < F4B) {
                load_lds16(gp4 + base + lane, sP + (size_t)base * 4);
                load_lds16(gt4 + base + lane, sT + (size_t)base * 4);
            }
        }
    }
    __syncthreads();   // compiler drains vmcnt(0) before s_barrier

    // ---- per-cell loss ----
    float s_box = 0.f, s_obj = 0.f, s_cls = 0.f;
    {
        float p[CH], t[CH];
        const float2* cp2 = reinterpret_cast<const float2*>(sP + tid * CH);
        const float2* ct2 = reinterpret_cast<const float2*>(sT + tid * CH);
        #pragma unroll
        for (int i = 0; i < CH / 2; ++i) {
            float2 v = cp2[i]; p[2*i] = v.x; p[2*i+1] = v.y;
            float2 w = ct2[i]; t[2*i] = w.x; t[2*i+1] = w.y;
        }

        const bool obj = t[4] > 0.f;

        float d0 = p[4] - t[4];
        float d1 = p[9] - t[9];
        float noobj = obj ? 0.f : (d0 * d0 + d1 * d1);

        const float tx = t[0] * INV_GS, ty = t[1] * INV_GS;
        const float tw = t[2], th = t[3];
        const float tax0 = tx - 0.5f * tw, tay0 = ty - 0.5f * th;
        const float tax1 = tx + 0.5f * tw, tay1 = ty + 0.5f * th;
        const float area_t = tw * th;

        float iou0, iou1;
        {
            float px = p[0] * INV_GS, py = p[1] * INV_GS, pw = p[2], ph = p[3];
            float ax0 = px - 0.5f * pw, ay0 = py - 0.5f * ph;
            float ax1 = px + 0.5f * pw, ay1 = py + 0.5f * ph;
            float iw = fmaxf(fminf(ax1, tax1) - fmaxf(ax0, tax0), 0.f);
            float ih = fmaxf(fminf(ay1, tay1) - fmaxf(ay0, tay0), 0.f);
            float inter = iw * ih;
            iou0 = inter / (pw * ph + area_t - inter);
        }
        {
            float px = p[5] * INV_GS, py = p[6] * INV_GS, pw = p[7], ph = p[8];
            float ax0 = px - 0.5f * pw, ay0 = py - 0.5f * ph;
            float ax1 = px + 0.5f * pw, ay1 = py + 0.5f * ph;
            float iw = fmaxf(fminf(ax1, tax1) - fmaxf(ax0, tax0), 0.f);
            float ih = fmaxf(fminf(ay1, tay1) - fmaxf(ay0, tay0), 0.f);
            float inter = iw * ih;
            iou1 = inter / (pw * ph + area_t - inter);
        }

        const bool  sel     = iou1 > iou0;            // first-max tie-break
        const float max_iou = fmaxf(iou0, iou1);
        const float rx = sel ? p[5] : p[0];
        const float ry = sel ? p[6] : p[1];
        const float rw = sel ? p[7] : p[2];
        const float rh = sel ? p[8] : p[3];
        const float rc = sel ? p[9] : p[4];

        if (obj) {
            float dx = rx - t[0], dy = ry - t[1];
            float sw = sqrtf(rw) - sqrtf(t[2]);
            float sh = sqrtf(rh) - sqrtf(t[3]);
            s_box = dx * dx + dy * dy + sw * sw + sh * sh;

            float dc = rc - max_iou;
            s_obj = dc * dc;

            float c = 0.f;
            #pragma unroll
            for (int k = 5 * NBX; k < CH; ++k) {
                float d = p[k] - t[k];
                c += d * d;
            }
            s_cls = c;
        }
        s_obj += L_NOOBJ * noobj;
    }

    // ---- wave + block reduce ----
    #pragma unroll
    for (int off = 32; off > 0; off >>= 1) {
        s_box += __shfl_down(s_box, off);
        s_obj += __shfl_down(s_obj, off);
        s_cls += __shfl_down(s_cls, off);
    }

    __shared__ float red[3][BLK / 64];
    if (lane == 0) { red[0][wid] = s_box; red[1][wid] = s_obj; red[2][wid] = s_cls; }
    __syncthreads();

    __shared__ bool isLast;
    if (tid == 0) {
        float b = red[0][0] + red[0][1] + red[0][2] + red[0][3];
        float o = red[1][0] + red[1][1] + red[1][2] + red[1][3];
        float c = red[2][0] + red[2][1] + red[2][2] + red[2][3];
        float* pp = part + (size_t)bid * 3;
        pp[0] = b; pp[1] = o; pp[2] = c;
        __threadfence();   // release partials to device scope (cross-XCD)
        unsigned int prev = __hip_atomic_fetch_add(counter, 1u,
                              __ATOMIC_ACQ_REL, __HIP_MEMORY_SCOPE_AGENT);
        isLast = (prev == (unsigned int)(NBLK - 1));
    }
    __syncthreads();

    // ---- last block reduces all partials (deterministic order) ----
    if (isLast) {
        __threadfence();   // acquire: invalidate caches before reading others' partials
        float s0 = 0.f, s1 = 0.f, s2 = 0.f;
        for (int i = tid; i < NBLK; i += BLK) {
            s0 += part[3 * i + 0];
            s1 += part[3 * i + 1];
            s2 += part[3 * i + 2];
        }
        #pragma unroll
        for (int off = 32; off > 0; off >>= 1) {
            s0 += __shfl_down(s0, off);
            s1 += __shfl_down(s1, off);
            s2 += __shfl_down(s2, off);
        }
        if (lane == 0) { red[0][wid] = s0; red[1][wid] = s1; red[2][wid] = s2; }
        __syncthreads();
        if (tid == 0) {
            float b = red[0][0] + red[0][1] + red[0][2] + red[0][3];
            float o = red[1][0] + red[1][1] + red[1][2] + red[1][3];
            float c = red[2][0] + red[2][1] + red[2][2] + red[2][3];
            out[0] = L_COORD * b * INV_BS;
            out[1] = o * INV_BS;
            out[2] = c * INV_BS;
        }
    }
}

extern "C" void kernel_launch(void* const* d_in, const int* in_sizes, int n_in,
                              void* d_out, int out_size, void* d_ws, size_t ws_size,
                              hipStream_t stream) {
    const float* preds   = (const float*)d_in[0];
    const float* targets = (const float*)d_in[1];
    float* out = (float*)d_out;

    unsigned int* counter = (unsigned int*)d_ws;
    float* part = (float*)d_ws + 16;   // 64B-aligned; NBLK*3 floats = 37632 B

    hipMemsetAsync(counter, 0, sizeof(unsigned int), stream);
    yolo_loss_fused<<<NBLK, BLK, 0, stream>>>(preds, targets, counter, part, out);
}